// Round 1
// baseline (736.009 us; speedup 1.0000x reference)
//
#include <hip/hip_runtime.h>

// GraphSAGE 2-layer, N=100000 nodes, E=1200000 edges, D: 64 -> 64 -> 32, fp32.
// Strategy: by linearity, aggregate raw features (segment mean) then dense
// transform. deg computed once (same graph both layers).

#define D1 64
#define D2 32

// One wave (64 lanes) per edge per iteration: lane d handles feature d.
__global__ __launch_bounds__(256)
void scatter_add_deg(const float* __restrict__ feat,
                     const int* __restrict__ src,
                     const int* __restrict__ dst,
                     float* __restrict__ agg,
                     float* __restrict__ deg,   // null on second pass
                     int E) {
    int gtid  = blockIdx.x * blockDim.x + threadIdx.x;
    int wave  = gtid >> 6;
    int lane  = threadIdx.x & 63;
    int nwave = (gridDim.x * blockDim.x) >> 6;
    for (int e = wave; e < E; e += nwave) {
        int s = src[e];
        int d = dst[e];
        float v = feat[(size_t)s * D1 + lane];
        atomicAdd(&agg[(size_t)d * D1 + lane], v);
        if (deg != nullptr && lane == 0) {
            atomicAdd(&deg[d], 1.0f);
        }
    }
}

// h = relu((agg/deg) @ Wl + b + x @ Wr), D1 x D1 weights in LDS.
// Block = 256 threads = 4 nodes x 64 output features.
__global__ __launch_bounds__(256)
void sage_layer1(const float* __restrict__ x,
                 const float* __restrict__ agg,
                 const float* __restrict__ deg,
                 const float* __restrict__ Wl,   // [64][64]
                 const float* __restrict__ Wr,   // [64][64]
                 const float* __restrict__ b,    // [64]
                 float* __restrict__ h,
                 int N) {
    __shared__ float sWl[D1 * D1];
    __shared__ float sWr[D1 * D1];
    __shared__ float sM[4 * D1];
    __shared__ float sX[4 * D1];

    for (int i = threadIdx.x; i < D1 * D1; i += 256) {
        sWl[i] = Wl[i];
        sWr[i] = Wr[i];
    }

    int node0 = blockIdx.x * 4;
    // stage 4 rows of agg and x, coalesced (256 threads = 4 rows x 64 cols)
    {
        int r = threadIdx.x >> 6;
        int c = threadIdx.x & 63;
        int nrow = node0 + r;
        float mv = 0.0f, xv = 0.0f;
        if (nrow < N) {
            mv = agg[(size_t)nrow * D1 + c];
            xv = x[(size_t)nrow * D1 + c];
        }
        sM[threadIdx.x] = mv;
        sX[threadIdx.x] = xv;
    }
    __syncthreads();

    int j     = threadIdx.x & 63;   // output feature
    int local = threadIdx.x >> 6;   // node within block (0..3)
    int node  = node0 + local;
    if (node < N) {
        float inv = 1.0f / fmaxf(deg[node], 1.0f);
        float acc = b[j];
        const float* mrow = &sM[local * D1];
        const float* xrow = &sX[local * D1];
        #pragma unroll
        for (int k = 0; k < D1; ++k) {
            acc = fmaf(mrow[k] * inv, sWl[k * D1 + j], acc);
            acc = fmaf(xrow[k],       sWr[k * D1 + j], acc);
        }
        h[(size_t)node * D1 + j] = fmaxf(acc, 0.0f);
    }
}

// out = (agg/deg) @ Wl + b + h @ Wr, weights [64][32].
// Block = 256 threads = 8 nodes x 32 output features.
__global__ __launch_bounds__(256)
void sage_layer2(const float* __restrict__ h,
                 const float* __restrict__ agg,
                 const float* __restrict__ deg,
                 const float* __restrict__ Wl,   // [64][32]
                 const float* __restrict__ Wr,   // [64][32]
                 const float* __restrict__ b,    // [32]
                 float* __restrict__ out,
                 int N) {
    __shared__ float sWl[D1 * D2];
    __shared__ float sWr[D1 * D2];
    __shared__ float sM[8 * D1];
    __shared__ float sX[8 * D1];

    for (int i = threadIdx.x; i < D1 * D2; i += 256) {
        sWl[i] = Wl[i];
        sWr[i] = Wr[i];
    }

    int node0 = blockIdx.x * 8;
    for (int i = threadIdx.x; i < 8 * D1; i += 256) {
        int nrow = node0 + (i >> 6);
        int c = i & 63;
        float mv = 0.0f, xv = 0.0f;
        if (nrow < N) {
            mv = agg[(size_t)nrow * D1 + c];
            xv = h[(size_t)nrow * D1 + c];
        }
        sM[i] = mv;
        sX[i] = xv;
    }
    __syncthreads();

    int j     = threadIdx.x & 31;   // output feature
    int local = threadIdx.x >> 5;   // node within block (0..7)
    int node  = node0 + local;
    if (node < N) {
        float inv = 1.0f / fmaxf(deg[node], 1.0f);
        float acc = b[j];
        const float* mrow = &sM[local * D1];
        const float* xrow = &sX[local * D1];
        #pragma unroll
        for (int k = 0; k < D1; ++k) {
            acc = fmaf(mrow[k] * inv, sWl[k * D2 + j], acc);
            acc = fmaf(xrow[k],       sWr[k * D2 + j], acc);
        }
        out[(size_t)node * D2 + j] = acc;
    }
}

extern "C" void kernel_launch(void* const* d_in, const int* in_sizes, int n_in,
                              void* d_out, int out_size, void* d_ws, size_t ws_size,
                              hipStream_t stream) {
    const float* x   = (const float*)d_in[0];
    const int*   ei  = (const int*)d_in[1];    // int32 on device
    const float* W1l = (const float*)d_in[2];
    const float* W1r = (const float*)d_in[3];
    const float* b1  = (const float*)d_in[4];
    const float* W2l = (const float*)d_in[5];
    const float* W2r = (const float*)d_in[6];
    const float* b2  = (const float*)d_in[7];
    float* out = (float*)d_out;

    int N = in_sizes[0] / D1;
    int E = in_sizes[1] / 2;
    const int* src = ei;       // edge_index[0]
    const int* dst = ei + E;   // edge_index[1]

    char* ws = (char*)d_ws;
    size_t degBytes = (((size_t)N * sizeof(float)) + 255) & ~(size_t)255;
    size_t aggBytes = (size_t)N * D1 * sizeof(float);
    float* deg = (float*)ws;
    float* agg = (float*)(ws + degBytes);
    float* h   = (float*)(ws + degBytes + aggBytes);

    // zero deg + agg (contiguous)
    hipMemsetAsync(ws, 0, degBytes + aggBytes, stream);

    const int SCATTER_BLOCKS = 2048;
    scatter_add_deg<<<SCATTER_BLOCKS, 256, 0, stream>>>(x, src, dst, agg, deg, E);

    sage_layer1<<<(N + 3) / 4, 256, 0, stream>>>(x, agg, deg, W1l, W1r, b1, h, N);

    hipMemsetAsync(ws + degBytes, 0, aggBytes, stream);

    scatter_add_deg<<<SCATTER_BLOCKS, 256, 0, stream>>>(h, src, dst, agg, nullptr, E);

    sage_layer2<<<(N + 7) / 8, 256, 0, stream>>>(h, agg, deg, W2l, W2r, b2, out, N);
}

// Round 2
// 578.688 us; speedup vs baseline: 1.2719x; 1.2719x over previous
//
#include <hip/hip_runtime.h>

// GraphSAGE 2-layer, N=100000, E=1200000, D: 64 -> 64 -> 32, fp32.
// R2: replace fp32 scatter-atomics (85% of R1 time) with a counting-sort CSR
// build (reused by both layers) + fused gather-mean + dense transform.

#define D1 64
#define D2 32

// ---- CSR build ----------------------------------------------------------

__global__ __launch_bounds__(256)
void count_deg(const int* __restrict__ dst, int* __restrict__ degi, int E) {
    int i = blockIdx.x * 256 + threadIdx.x;
    if (i < E) atomicAdd(&degi[dst[i]], 1);
}

// per-block sums of degi
__global__ __launch_bounds__(256)
void block_sums(const int* __restrict__ degi, int* __restrict__ partial, int N) {
    __shared__ int s[256];
    int i = blockIdx.x * 256 + threadIdx.x;
    int t = threadIdx.x;
    s[t] = (i < N) ? degi[i] : 0;
    __syncthreads();
    for (int off = 128; off > 0; off >>= 1) {
        if (t < off) s[t] += s[t + off];
        __syncthreads();
    }
    if (t == 0) partial[blockIdx.x] = s[0];
}

// exclusive scan of partial[NB], NB <= 512, single block of 512
__global__ __launch_bounds__(512)
void scan_partials(int* __restrict__ partial, int NB) {
    __shared__ int s[512];
    int t = threadIdx.x;
    int v = (t < NB) ? partial[t] : 0;
    s[t] = v;
    __syncthreads();
    for (int off = 1; off < 512; off <<= 1) {
        int add = (t >= off) ? s[t - off] : 0;
        __syncthreads();
        s[t] += add;
        __syncthreads();
    }
    if (t < NB) partial[t] = s[t] - v;   // exclusive
}

// per-block exclusive scan + offset -> rowstart, cursor
__global__ __launch_bounds__(256)
void write_rowstart(const int* __restrict__ degi, const int* __restrict__ partial,
                    int* __restrict__ rowstart, int* __restrict__ cursor,
                    int N, int E) {
    __shared__ int s[256];
    int i = blockIdx.x * 256 + threadIdx.x;
    int t = threadIdx.x;
    int v = (i < N) ? degi[i] : 0;
    s[t] = v;
    __syncthreads();
    for (int off = 1; off < 256; off <<= 1) {
        int add = (t >= off) ? s[t - off] : 0;
        __syncthreads();
        s[t] += add;
        __syncthreads();
    }
    int excl = s[t] - v + partial[blockIdx.x];
    if (i < N) {
        rowstart[i] = excl;
        cursor[i]   = excl;
    }
    if (i == 0) rowstart[N] = E;
}

__global__ __launch_bounds__(256)
void bucket_fill(const int* __restrict__ src, const int* __restrict__ dst,
                 int* __restrict__ cursor, int* __restrict__ nbr, int E) {
    int i = blockIdx.x * 256 + threadIdx.x;
    if (i < E) {
        int d = dst[i];
        int p = atomicAdd(&cursor[d], 1);
        nbr[p] = src[i];
    }
}

// ---- fused layer: out = act((mean nbrs feat) @ Wl + b + feat @ Wr) ------
// Block = 256 threads = 4 waves = 4 nodes. Wave lane = feature index.

template <int DOUT, bool RELU>
__global__ __launch_bounds__(256)
void sage_fused(const float* __restrict__ feat,
                const int* __restrict__ rowstart,
                const int* __restrict__ nbr,
                const float* __restrict__ Wl,   // [64][DOUT]
                const float* __restrict__ Wr,   // [64][DOUT]
                const float* __restrict__ bias, // [DOUT]
                float* __restrict__ outp,
                int N) {
    __shared__ float sWl[D1 * DOUT];
    __shared__ float sWr[D1 * DOUT];
    __shared__ float sB[DOUT];
    __shared__ float sM[4][D1];
    __shared__ float sX[4][D1];

    for (int i = threadIdx.x; i < D1 * DOUT; i += 256) {
        sWl[i] = Wl[i];
        sWr[i] = Wr[i];
    }
    if (threadIdx.x < DOUT) sB[threadIdx.x] = bias[threadIdx.x];

    int w = threadIdx.x >> 6;
    int lane = threadIdx.x & 63;
    int node = blockIdx.x * 4 + w;

    float mean = 0.0f, xv = 0.0f;
    if (node < N) {
        int r0 = rowstart[node];
        int r1 = rowstart[node + 1];
        float acc = 0.0f;
        for (int i = r0; i < r1; ++i) {
            int s = nbr[i];                       // broadcast load
            acc += feat[(size_t)s * D1 + lane];   // 256B coalesced row
        }
        mean = acc / fmaxf((float)(r1 - r0), 1.0f);
        xv = feat[(size_t)node * D1 + lane];
    }
    sM[w][lane] = mean;
    sX[w][lane] = xv;
    __syncthreads();

    if (node >= N) return;

    if (DOUT == 64) {
        int j = lane;
        float acc = sB[j];
        #pragma unroll
        for (int k = 0; k < D1; ++k) {
            acc = fmaf(sM[w][k], sWl[k * DOUT + j], acc);
            acc = fmaf(sX[w][k], sWr[k * DOUT + j], acc);
        }
        if (RELU) acc = fmaxf(acc, 0.0f);
        outp[(size_t)node * DOUT + j] = acc;
    } else {
        // DOUT==32: all 64 lanes busy — halves split the k-range, shfl-combine
        int j    = lane & (DOUT - 1);
        int half = lane >> 5;
        float acc = 0.0f;
        #pragma unroll
        for (int kk = 0; kk < 32; ++kk) {
            int k = half * 32 + kk;
            acc = fmaf(sM[w][k], sWl[k * DOUT + j], acc);
            acc = fmaf(sX[w][k], sWr[k * DOUT + j], acc);
        }
        acc += __shfl_xor(acc, 32, 64);
        if (half == 0) {
            float r = acc + sB[j];
            if (RELU) r = fmaxf(r, 0.0f);
            outp[(size_t)node * DOUT + j] = r;
        }
    }
}

// ---- launch -------------------------------------------------------------

extern "C" void kernel_launch(void* const* d_in, const int* in_sizes, int n_in,
                              void* d_out, int out_size, void* d_ws, size_t ws_size,
                              hipStream_t stream) {
    const float* x   = (const float*)d_in[0];
    const int*   ei  = (const int*)d_in[1];
    const float* W1l = (const float*)d_in[2];
    const float* W1r = (const float*)d_in[3];
    const float* b1  = (const float*)d_in[4];
    const float* W2l = (const float*)d_in[5];
    const float* W2r = (const float*)d_in[6];
    const float* b2  = (const float*)d_in[7];
    float* out = (float*)d_out;

    int N = in_sizes[0] / D1;
    int E = in_sizes[1] / 2;
    const int* src = ei;
    const int* dst = ei + E;

    // workspace layout (all 256B-aligned)
    char* ws = (char*)d_ws;
    auto alignup = [](size_t v) { return (v + 255) & ~(size_t)255; };
    size_t off = 0;
    int* degi     = (int*)(ws + off); off += alignup((size_t)N * 4);
    int* partial  = (int*)(ws + off); off += alignup(512 * 4);
    int* rowstart = (int*)(ws + off); off += alignup((size_t)(N + 1) * 4);
    int* cursor   = (int*)(ws + off); off += alignup((size_t)N * 4);
    int* nbr      = (int*)(ws + off); off += alignup((size_t)E * 4);
    float* h      = (float*)(ws + off);

    int NB = (N + 255) / 256;     // 391 <= 512

    hipMemsetAsync(degi, 0, (size_t)N * 4, stream);

    int eb = (E + 255) / 256;
    count_deg<<<eb, 256, 0, stream>>>(dst, degi, E);
    block_sums<<<NB, 256, 0, stream>>>(degi, partial, N);
    scan_partials<<<1, 512, 0, stream>>>(partial, NB);
    write_rowstart<<<NB, 256, 0, stream>>>(degi, partial, rowstart, cursor, N, E);
    bucket_fill<<<eb, 256, 0, stream>>>(src, dst, cursor, nbr, E);

    int nb4 = (N + 3) / 4;
    sage_fused<64, true ><<<nb4, 256, 0, stream>>>(x, rowstart, nbr, W1l, W1r, b1, h, N);
    sage_fused<32, false><<<nb4, 256, 0, stream>>>(h, rowstart, nbr, W2l, W2r, b2, out, N);
}